// Round 13
// baseline (174.036 us; speedup 1.0000x reference)
//
#include <hip/hip_runtime.h>
#include <hip/hip_fp16.h>

#define HID 512
#define GC  640
#define CC  320
#define GG  2
#define DHALF 128
#define MARGIN 0.004f
#define FB 4

typedef __attribute__((ext_vector_type(8))) _Float16 half8;
typedef __attribute__((ext_vector_type(4))) float float4v;

__global__ __launch_bounds__(256) void zero_misc(float* meanAcc, int* cnt) {
    for (int i = threadIdx.x; i < GC; i += 256) meanAcc[i] = 0.f;
    if (threadIdx.x < 2) cnt[threadIdx.x] = 0;
}

// Pack W (fp32 [640][512]) into fp16 MFMA-frag order:
// frag t=(g*320 + kk*20 + j): lane l holds W[g*320+j*16+(l&15)][kk*32+(l>>4)*8 ..+7]
// stored contiguously at Wpk + t*512 + l*8  -> B-frag load = coalesced 1KB.
__global__ __launch_bounds__(256) void pack_w(
    const float* __restrict__ W, unsigned short* __restrict__ Wpk)
{
    const int t    = blockIdx.x * 4 + (threadIdx.x >> 6);   // 0..639
    const int lane = threadIdx.x & 63;
    const int g = t / 320, rem = t % 320, kk = rem / 20, j = rem % 20;
    const int row = g * 320 + j * 16 + (lane & 15);
    const int k   = kk * 32 + (lane >> 4) * 8;
    const float* src = W + (size_t)row * HID + k;
    float4 xa = *(const float4*)src;
    float4 xb = *(const float4*)(src + 4);
    half8 h;
    h[0] = (_Float16)xa.x; h[1] = (_Float16)xa.y;
    h[2] = (_Float16)xa.z; h[3] = (_Float16)xa.w;
    h[4] = (_Float16)xb.x; h[5] = (_Float16)xb.y;
    h[6] = (_Float16)xb.z; h[7] = (_Float16)xb.w;
    *(half8*)(Wpk + (size_t)t * 512 + lane * 8) = h;
}

// Barrier-free wave-autonomous fused kernel. ONLY change vs round 12:
// __launch_bounds__(256, 2) -> 256-reg cap so acc[20]=80 + epilogue state fits
// WITHOUT scratch spills (every acc[20] round so far was capped at 128 and spilled).
__global__ __launch_bounds__(256, 2) void fused(
    const float* __restrict__ X, const unsigned short* __restrict__ Wpk,
    const float* __restrict__ bq, const float* __restrict__ gum,
    const float* __restrict__ cv, float* __restrict__ out,
    float* __restrict__ meanAcc, int* __restrict__ cnt,
    int* __restrict__ flags0, int* __restrict__ flags1)
{
    __shared__ float rep[4][4][328];    // [wave][token-slot][padded cols] 21KB
    __shared__ float bqs[CC];
    __shared__ float smean[CC];

    const int tid  = threadIdx.x;
    const int lane = tid & 63;
    const int wv   = tid >> 6;          // 0..3
    const int lq   = lane & 15;
    const int q    = lane >> 4;

    int bid = blockIdx.x, nwg = gridDim.x;
    int swz = ((nwg & 7) == 0) ? (bid & 7) * (nwg >> 3) + (bid >> 3) : bid;
    const int g    = swz & 1;
    const int tok0 = (swz >> 1) * 64 + wv * 16;     // wave's token base
    int* flagsg = g ? flags1 : flags0;

    for (int i = tid; i < CC; i += 256) { bqs[i] = bq[g * CC + i]; smean[i] = 0.f; }
    __syncthreads();

    // A: lane reads X[tok0+lq][kk*32 + q*8 ..+7] (fp32)
    const float* xsrc = X + (size_t)(tok0 + lq) * HID + q * 8;
    // B: packed frags for this group
    const unsigned short* bsrc = Wpk + (size_t)g * 163840 + lane * 8;

    float4v acc[20];
#pragma unroll
    for (int j = 0; j < 20; ++j) acc[j] = (float4v){0.f, 0.f, 0.f, 0.f};

    for (int ko = 0; ko < 4; ++ko) {
#pragma unroll
        for (int ki = 0; ki < 4; ++ki) {
            const int kk = ko * 4 + ki;
            float4 xa = *(const float4*)(xsrc + kk * 32);
            float4 xb = *(const float4*)(xsrc + kk * 32 + 4);
            half8 a;
            a[0] = (_Float16)xa.x; a[1] = (_Float16)xa.y;
            a[2] = (_Float16)xa.z; a[3] = (_Float16)xa.w;
            a[4] = (_Float16)xb.x; a[5] = (_Float16)xb.y;
            a[6] = (_Float16)xb.z; a[7] = (_Float16)xb.w;
            const unsigned short* bk = bsrc + kk * 10240;
#pragma unroll
            for (int j = 0; j < 20; ++j) {
                half8 b = *(const half8*)(bk + j * 512);
                acc[j] = __builtin_amdgcn_mfma_f32_16x16x32_f16(a, b, acc[j], 0, 0, 0);
            }
        }
        __syncthreads();   // drift control: keeps the 4 waves' B streams L1-coherent
    }

    // ---- epilogue (wave-local), r force-unrolled (static acc indices) ----
    float macc[20];
#pragma unroll
    for (int j = 0; j < 20; ++j) macc[j] = 0.f;
    const int cb = lq * 20;

#pragma unroll
    for (int r = 0; r < 4; ++r) {
        // phase A: lane (q,lq) owns token q*4+r; scatter its 20 cols
#pragma unroll
        for (int j = 0; j < 20; ++j)
            rep[wv][q][j * 16 + lq] = acc[j][r] + bqs[j * 16 + lq];
        asm volatile("s_waitcnt lgkmcnt(0)" ::: "memory");   // wave-local fence

        // phase B: lane -> token-slot q, contiguous codes cb..cb+19
        const int tglob = tok0 + q * 4 + r;
        const float* rrow = &rep[wv][q][cb];
        const float* grow = gum + ((size_t)tglob * GG + g) * CC + cb;

        float s = 0.f;
        float b = -3.0e38f; int bi = 0; float s2 = -3.0e38f;
#pragma unroll
        for (int jj = 0; jj < 5; ++jj) {
            float4 lv = *(const float4*)(rrow + jj * 4);
            float4 gv = *(const float4*)(grow + jj * 4);
            float lf[4] = {lv.x, lv.y, lv.z, lv.w};
            float gf[4] = {gv.x, gv.y, gv.z, gv.w};
#pragma unroll
            for (int t = 0; t < 4; ++t) {
                float v = lf[t] + gf[t];
                if (v > b)       { s2 = b; b = v; bi = cb + jj * 4 + t; }
                else if (v > s2) { s2 = v; }
                s += __expf(lf[t]);
            }
        }
        // fused 4-step reduce within the 16-lane token group
#pragma unroll
        for (int m = 1; m < 16; m <<= 1) {
            float os  = __shfl_xor(s,  m, 64);
            float ob  = __shfl_xor(b,  m, 64);
            int   obi = __shfl_xor(bi, m, 64);
            float os2 = __shfl_xor(s2, m, 64);
            s += os;
            if (ob > b || (ob == b && obi < bi)) { s2 = fmaxf(os2, b); b = ob; bi = obi; }
            else                                 { s2 = fmaxf(s2, ob); }
        }
        float inv = 1.f / s;
        // second pass from LDS (keeps live regs low)
#pragma unroll
        for (int jj = 0; jj < 5; ++jj) {
            float4 lv = *(const float4*)(rrow + jj * 4);
            macc[jj*4+0] += __expf(lv.x) * inv;
            macc[jj*4+1] += __expf(lv.y) * inv;
            macc[jj*4+2] += __expf(lv.z) * inv;
            macc[jj*4+3] += __expf(lv.w) * inv;
        }

        if (lq == 0 && (b - s2) < MARGIN) {
            int p = atomicAdd(&cnt[g], 1);
            flagsg[p] = tglob;
        }
        const float* cvp = cv + ((size_t)(g * CC + bi)) * DHALF + lq * 8;
        float4 c0v = *(const float4*)cvp;
        float4 c1v = *(const float4*)(cvp + 4);
        float* op = out + (size_t)tglob * 256 + g * DHALF + lq * 8;
        *(float4*)op       = c0v;
        *(float4*)(op + 4) = c1v;
        asm volatile("s_waitcnt lgkmcnt(0)" ::: "memory");   // reads done before overwrite
    }

    // fold macc across token-slots (q), then block smean, then global
#pragma unroll
    for (int j = 0; j < 20; ++j) {
        macc[j] += __shfl_xor(macc[j], 16, 64);
        macc[j] += __shfl_xor(macc[j], 32, 64);
    }
    if (lane < 16) {
#pragma unroll
        for (int j = 0; j < 20; ++j)
            atomicAdd(&smean[cb + j], macc[j]);
    }
    __syncthreads();
    for (int i = tid; i < CC; i += 256)
        atomicAdd(&meanAcc[g * CC + i], smean[i]);
}

// Exact fp32 recompute for flagged rows: FB rows share one W pass.
__global__ __launch_bounds__(320) void fixup(
    const float* __restrict__ X, const float* __restrict__ W,
    const float* __restrict__ bq, const float* __restrict__ gum,
    const float* __restrict__ cv, float* __restrict__ out,
    const int* __restrict__ flags0, const int* __restrict__ flags1,
    const int* __restrict__ cnt)
{
    __shared__ float xs[FB][HID];
    __shared__ float vals[FB][CC];
    __shared__ int stok[FB];
    const int tid = threadIdx.x;
    const int n0 = cnt[0], n1 = cnt[1];
    const int nb0 = (n0 + FB - 1) / FB;
    const int nb1 = (n1 + FB - 1) / FB;

    for (int bb = blockIdx.x; bb < nb0 + nb1; bb += gridDim.x) {
        const int g    = (bb < nb0) ? 0 : 1;
        const int lb   = (bb < nb0) ? bb : bb - nb0;
        const int n    = g ? n1 : n0;
        const int* fl  = g ? flags1 : flags0;
        const int r0   = lb * FB;
        const int nr   = (n - r0 < FB) ? (n - r0) : FB;

        if (tid < FB) {
            int idx = r0 + tid;
            if (idx >= n) idx = n - 1;
            stok[tid] = fl[idx];
        }
        __syncthreads();
        for (int i = tid; i < FB * (HID / 4); i += 320) {
            int r = i >> 7, k4 = i & 127;
            *(float4*)&xs[r][k4 * 4] = *(const float4*)(X + (size_t)stok[r] * HID + k4 * 4);
        }
        __syncthreads();

        {
            const int c = tid;
            if (c < CC) {
                const float* wr = W + (size_t)(g * CC + c) * HID;
                float acc[FB];
#pragma unroll
                for (int r = 0; r < FB; ++r) acc[r] = 0.f;
                for (int k4 = 0; k4 < HID / 4; ++k4) {
                    float4 w4 = *(const float4*)(wr + k4 * 4);
#pragma unroll
                    for (int r = 0; r < FB; ++r) {
                        float4 xv = *(const float4*)&xs[r][k4 * 4];
                        acc[r] = fmaf(xv.x, w4.x, acc[r]);
                        acc[r] = fmaf(xv.y, w4.y, acc[r]);
                        acc[r] = fmaf(xv.z, w4.z, acc[r]);
                        acc[r] = fmaf(xv.w, w4.w, acc[r]);
                    }
                }
                float bias = bq[g * CC + c];
#pragma unroll
                for (int r = 0; r < FB; ++r)
                    vals[r][c] = acc[r] + bias + gum[((size_t)stok[r] * GG + g) * CC + c];
            }
        }
        __syncthreads();

        const int lane = tid & 63;
        const int wvv  = tid >> 6;
        if (wvv < FB) {
            const int r = wvv;
            if (r < nr) {
                float b = -3.0e38f; int bi = 0;
#pragma unroll
                for (int j = 0; j < 5; ++j) {
                    int c = lane + j * 64;
                    float v = vals[r][c];
                    if (v > b || (v == b && c < bi)) { b = v; bi = c; }
                }
#pragma unroll
                for (int m = 32; m; m >>= 1) {
                    float ob = __shfl_xor(b, m, 64);
                    int  obi = __shfl_xor(bi, m, 64);
                    if (ob > b || (ob == b && obi < bi)) { b = ob; bi = obi; }
                }
                int tok = stok[r];
                float2 cvv = *(const float2*)(cv + ((size_t)(g * CC + bi)) * DHALF + lane * 2);
                *(float2*)(out + (size_t)tok * 256 + g * DHALF + lane * 2) = cvv;
            }
        }
        __syncthreads();
    }
}

__global__ __launch_bounds__(256) void perpk(
    const float* __restrict__ meanAcc, float* __restrict__ outp, int ntot)
{
    __shared__ float red0[256];
    __shared__ float red1[256];
    const float invn = 1.f / (float)ntot;
    float h0 = 0.f, h1 = 0.f;
    for (int c = threadIdx.x; c < CC; c += 256) {
        float p0 = meanAcc[c]      * invn;
        float p1 = meanAcc[CC + c] * invn;
        h0 -= p0 * logf(p0 + 1e-7f);
        h1 -= p1 * logf(p1 + 1e-7f);
    }
    red0[threadIdx.x] = h0; red1[threadIdx.x] = h1;
    __syncthreads();
    for (int s = 128; s; s >>= 1) {
        if (threadIdx.x < (unsigned)s) {
            red0[threadIdx.x] += red0[threadIdx.x + s];
            red1[threadIdx.x] += red1[threadIdx.x + s];
        }
        __syncthreads();
    }
    if (threadIdx.x == 0) outp[0] = expf(red0[0]) + expf(red1[0]);
}

extern "C" void kernel_launch(void* const* d_in, const int* in_sizes, int n_in,
                              void* d_out, int out_size, void* d_ws, size_t ws_size,
                              hipStream_t stream) {
    const float* x      = (const float*)d_in[0];
    const float* gumbel = (const float*)d_in[1];
    const float* Wq     = (const float*)d_in[2];
    const float* bq     = (const float*)d_in[3];
    const float* cv     = (const float*)d_in[4];
    float* out = (float*)d_out;

    const int NT = in_sizes[0] / HID;       // 32768 tokens

    char* wsc = (char*)d_ws;
    float* meanAcc = (float*)wsc;                          // 640 f
    int*   cnt     = (int*)(wsc + 2560);                   // 2 ints
    int*   flags0  = (int*)(wsc + 4096);                   // 32768 ints
    int*   flags1  = (int*)(wsc + 135168);                 // 32768 ints
    unsigned short* Wpk = (unsigned short*)(wsc + 266240); // 640*512 f16 packed

    zero_misc<<<1, 256, 0, stream>>>(meanAcc, cnt);
    pack_w<<<160, 256, 0, stream>>>(Wq, Wpk);

    const int nwg = (NT / 64) * 2;          // 1024 blocks
    fused<<<nwg, 256, 0, stream>>>(x, Wpk, bq, gumbel, cv, out,
                                   meanAcc, cnt, flags0, flags1);

    fixup<<<256, 320, 0, stream>>>(x, Wq, bq, gumbel, cv, out, flags0, flags1, cnt);
    perpk<<<1, 256, 0, stream>>>(meanAcc, out + (size_t)out_size - 1, NT);
}

// Round 14
// 171.804 us; speedup vs baseline: 1.0130x; 1.0130x over previous
//
#include <hip/hip_runtime.h>
#include <hip/hip_fp16.h>

#define HID 512
#define GC  640
#define CC  320
#define GG  2
#define DHALF 128
#define MARGIN 0.004f
#define FB 4

typedef __attribute__((ext_vector_type(8))) _Float16 half8;
typedef __attribute__((ext_vector_type(4))) float float4v;

__device__ __forceinline__ void gload16(const void* g, void* l) {
    __builtin_amdgcn_global_load_lds(
        (const __attribute__((address_space(1))) void*)(unsigned long long)g,
        (__attribute__((address_space(3))) void*)(unsigned)(unsigned long long)l,
        16, 0, 0);
}

__device__ __forceinline__ half8 cvt8(float4 a, float4 b) {
    half8 h;
    h[0] = (_Float16)a.x; h[1] = (_Float16)a.y;
    h[2] = (_Float16)a.z; h[3] = (_Float16)a.w;
    h[4] = (_Float16)b.x; h[5] = (_Float16)b.y;
    h[6] = (_Float16)b.z; h[7] = (_Float16)b.w;
    return h;
}

__global__ __launch_bounds__(256) void zero_misc(float* meanAcc, int* cnt) {
    for (int i = threadIdx.x; i < GC; i += 256) meanAcc[i] = 0.f;
    if (threadIdx.x < 2) cnt[threadIdx.x] = 0;
}

__global__ __launch_bounds__(256) void convert_f16(
    const float* __restrict__ in, unsigned short* __restrict__ out, int n8)
{
    int i = blockIdx.x * 256 + threadIdx.x;
    if (i >= n8) return;
    const float4* p = (const float4*)in + (size_t)i * 2;
    float4 v0 = p[0], v1 = p[1];
    float f[8] = {v0.x, v0.y, v0.z, v0.w, v1.x, v1.y, v1.z, v1.w};
    unsigned r[4];
#pragma unroll
    for (int j = 0; j < 4; ++j) {
        __half2 hh = __float22half2_rn(make_float2(f[2*j], f[2*j+1]));
        r[j] = __builtin_bit_cast(unsigned, hh);
    }
    uint4 o = {r[0], r[1], r[2], r[3]};
    *(uint4*)(out + (size_t)i * 8) = o;
}

// Fused GEMM + epilogue with counted-vmcnt 3-deep B pipeline (T3+T4).
// Block: 64 tokens x 320 codes (one group). 8 waves = 4 row-groups x 2 col-halves.
// B: gload_lds into 3 rotating 20KB buffers, kchunk-major [4][320][8] (2-way free).
// A: per-lane global fp32 -> reg -> cvt (no LDS). Raw s_barrier + counted vmcnt:
// B(k+2) loads stay outstanding across the barrier (never drained to 0 mid-loop).
__global__ __launch_bounds__(512, 2) void fused(
    const float* __restrict__ X, const unsigned short* __restrict__ Wh,
    const float* __restrict__ bq, const float* __restrict__ gum,
    const float* __restrict__ cv, float* __restrict__ out,
    float* __restrict__ meanAcc, int* __restrict__ cnt,
    int* __restrict__ flags0, int* __restrict__ flags1)
{
    __shared__ __align__(16) char smemc[61440];   // 3 x 20KB B buffers
    __shared__ float bqs[CC];
    float* rep   = (float*)smemc;                 // [16][324] (post-K-loop overlay)
    float* smean = (float*)(smemc + 40960);       // buf2 region (post-rep)

    const int tid  = threadIdx.x;
    const int lane = tid & 63;
    const int wid  = tid >> 6;          // 0..7
    const int wr   = wid >> 1, wc = wid & 1;
    const int lq   = lane & 15, q = lane >> 4;

    int bid = blockIdx.x, nwg = gridDim.x;
    int swz = ((nwg & 7) == 0) ? (bid & 7) * (nwg >> 3) + (bid >> 3) : bid;
    const int g    = swz & 1;
    const int tok0 = (swz >> 1) * 64;
    int* flagsg = g ? flags1 : flags0;

    for (int i = tid; i < CC; i += 512) bqs[i] = bq[g * CC + i];

    // B staging slots: 20 issues/step; waves 0-3 own 3, waves 4-7 own 2.
    const int nb = (wid < 4) ? 3 : 2;
    int sl[3];
    if (wid < 4) { sl[0] = wid * 3; sl[1] = sl[0] + 1; sl[2] = sl[0] + 2; }
    else         { sl[0] = 12 + (wid - 4) * 2; sl[1] = sl[0] + 1; sl[2] = sl[0]; }
    const unsigned short* bsrcp[3];
#pragma unroll
    for (int u = 0; u < 3; ++u) {
        int c = sl[u] * 64 + lane;          // chunk = kc*320 + row
        int kc = c / 320, row = c - kc * 320;
        bsrcp[u] = Wh + ((size_t)(g * CC + row)) * HID + kc * 8;
    }
    const float* xsrc = X + (size_t)(tok0 + wr * 16 + lq) * HID + q * 8;

    float4v acc[10];
#pragma unroll
    for (int j = 0; j < 10; ++j) acc[j] = (float4v){0.f, 0.f, 0.f, 0.f};

    auto issueB = [&](int kstep) {
        unsigned short* dbase = (unsigned short*)(smemc + (kstep % 3) * 20480);
#pragma unroll
        for (int u = 0; u < 3; ++u)
            if (u < nb) gload16(bsrcp[u] + kstep * 32, dbase + sl[u] * 512);
    };
    auto compute10 = [&](int buf, half8 a) {
        const char* bb = smemc + buf * 20480 + q * 5120 + wc * 2560 + lq * 16;
#pragma unroll
        for (int j = 0; j < 10; ++j) {
            half8 b = *(const half8*)(bb + j * 256);
            acc[j] = __builtin_amdgcn_mfma_f32_16x16x32_f16(a, b, acc[j], 0, 0, 0);
        }
    };

    // ---- prologue: A(0); B(0) | fence | B(1)  (FIFO order matters)
    float4 nxa = *(const float4*)xsrc;
    float4 nxb = *(const float4*)(xsrc + 4);
    issueB(0);
    __builtin_amdgcn_sched_barrier(0);
    issueB(1);

    // ---- kk = 0: allow B(1) outstanding
    if (wid < 4) asm volatile("s_waitcnt vmcnt(3)" ::: "memory");
    else         asm volatile("s_waitcnt vmcnt(2)" ::: "memory");
    __builtin_amdgcn_s_barrier();
    __builtin_amdgcn_sched_barrier(0);
    {
        half8 a = cvt8(nxa, nxb);
        nxa = *(const float4*)(xsrc + 32);
        nxb = *(const float4*)(xsrc + 36);
        issueB(2);
        compute10(0, a);
    }

    // ---- kk = 1..13: allow A(kk)+B(kk+1) outstanding (5 / 4)
    for (int kk = 1; kk <= 13; ++kk) {
        if (wid < 4) asm volatile("s_waitcnt vmcnt(5)" ::: "memory");
        else         asm volatile("s_waitcnt vmcnt(4)" ::: "memory");
        __builtin_amdgcn_s_barrier();
        __builtin_amdgcn_sched_barrier(0);
        half8 a = cvt8(nxa, nxb);
        nxa = *(const float4*)(xsrc + (kk + 1) * 32);
        nxb = *(const float4*)(xsrc + (kk + 1) * 32 + 4);
        issueB(kk + 2);
        compute10(kk % 3, a);
    }

    // ---- kk = 14 (no B(16))
    if (wid < 4) asm volatile("s_waitcnt vmcnt(5)" ::: "memory");
    else         asm volatile("s_waitcnt vmcnt(4)" ::: "memory");
    __builtin_amdgcn_s_barrier();
    __builtin_amdgcn_sched_barrier(0);
    {
        half8 a = cvt8(nxa, nxb);
        nxa = *(const float4*)(xsrc + 15 * 32);
        nxb = *(const float4*)(xsrc + 15 * 32 + 4);
        compute10(2, a);
    }

    // ---- kk = 15: only A(15) outstanding
    asm volatile("s_waitcnt vmcnt(2)" ::: "memory");
    __builtin_amdgcn_s_barrier();
    __builtin_amdgcn_sched_barrier(0);
    {
        half8 a = cvt8(nxa, nxb);
        compute10(0, a);
    }
    __syncthreads();    // all waves done with B buffers; rep overlay now safe

    // ---- epilogue (R10's proven repack form) ----
    float macc[20];
#pragma unroll
    for (int j = 0; j < 20; ++j) macc[j] = 0.f;
    const int gg = tid >> 4, lql = tid & 15, cb = lql * 20;

#pragma unroll
    for (int r = 0; r < 4; ++r) {
        const int slot = wr * 4 + q;
#pragma unroll
        for (int j = 0; j < 10; ++j) {
            const int c = wc * 160 + j * 16 + lq;
            rep[slot * 324 + c] = acc[j][r] + bqs[c];
        }
        __syncthreads();

        if (gg < 16) {
            const int rowL  = (gg >> 2) * 16 + (gg & 3) * 4 + r;
            const int tglob = tok0 + rowL;
            const float* grow = gum + ((size_t)tglob * GG + g) * CC + cb;
            const float* rrow = rep + gg * 324 + cb;

            float s = 0.f;
            float b = -3.0e38f; int bi = 0; float s2 = -3.0e38f;
#pragma unroll
            for (int jj = 0; jj < 5; ++jj) {
                float4 lv = *(const float4*)(rrow + jj * 4);
                float4 gv = *(const float4*)(grow + jj * 4);
                float lf[4] = {lv.x, lv.y, lv.z, lv.w};
                float gf[4] = {gv.x, gv.y, gv.z, gv.w};
#pragma unroll
                for (int t = 0; t < 4; ++t) {
                    float v = lf[t] + gf[t];
                    if (v > b)       { s2 = b; b = v; bi = cb + jj * 4 + t; }
                    else if (v > s2) { s2 = v; }
                    s += __expf(lf[t]);
                }
            }
#pragma unroll
            for (int m = 1; m < 16; m <<= 1) {
                float os  = __shfl_xor(s,  m, 64);
                float ob  = __shfl_xor(b,  m, 64);
                int   obi = __shfl_xor(bi, m, 64);
                float os2 = __shfl_xor(s2, m, 64);
                s += os;
                if (ob > b || (ob == b && obi < bi)) { s2 = fmaxf(os2, b); b = ob; bi = obi; }
                else                                 { s2 = fmaxf(s2, ob); }
            }
            float inv = 1.f / s;
#pragma unroll
            for (int jj = 0; jj < 5; ++jj) {
                float4 lv = *(const float4*)(rrow + jj * 4);
                macc[jj*4+0] += __expf(lv.x) * inv;
                macc[jj*4+1] += __expf(lv.y) * inv;
                macc[jj*4+2] += __expf(lv.z) * inv;
                macc[jj*4+3] += __expf(lv.w) * inv;
            }

            if (lql == 0 && (b - s2) < MARGIN) {
                int p = atomicAdd(&cnt[g], 1);
                flagsg[p] = tglob;
            }
            const float* cvp = cv + ((size_t)(g * CC + bi)) * DHALF + lql * 8;
            float4 c0v = *(const float4*)cvp;
            float4 c1v = *(const float4*)(cvp + 4);
            float* op = out + (size_t)tglob * 256 + g * DHALF + lql * 8;
            *(float4*)op       = c0v;
            *(float4*)(op + 4) = c1v;
        }
        __syncthreads();
    }

    for (int i = tid; i < CC; i += 512) smean[i] = 0.f;
    __syncthreads();
    if (tid < 256) {
#pragma unroll
        for (int j = 0; j < 20; ++j)
            atomicAdd(&smean[cb + j], macc[j]);
    }
    __syncthreads();
    for (int i = tid; i < CC; i += 512)
        atomicAdd(&meanAcc[g * CC + i], smean[i]);
}

// Exact fp32 recompute for flagged rows: FB rows share one W pass.
__global__ __launch_bounds__(320) void fixup(
    const float* __restrict__ X, const float* __restrict__ W,
    const float* __restrict__ bq, const float* __restrict__ gum,
    const float* __restrict__ cv, float* __restrict__ out,
    const int* __restrict__ flags0, const int* __restrict__ flags1,
    const int* __restrict__ cnt)
{
    __shared__ float xs[FB][HID];
    __shared__ float vals[FB][CC];
    __shared__ int stok[FB];
    const int tid = threadIdx.x;
    const int n0 = cnt[0], n1 = cnt[1];
    const int nb0 = (n0 + FB - 1) / FB;
    const int nb1 = (n1 + FB - 1) / FB;

    for (int bb = blockIdx.x; bb < nb0 + nb1; bb += gridDim.x) {
        const int g    = (bb < nb0) ? 0 : 1;
        const int lb   = (bb < nb0) ? bb : bb - nb0;
        const int n    = g ? n1 : n0;
        const int* fl  = g ? flags1 : flags0;
        const int r0   = lb * FB;
        const int nr   = (n - r0 < FB) ? (n - r0) : FB;

        if (tid < FB) {
            int idx = r0 + tid;
            if (idx >= n) idx = n - 1;
            stok[tid] = fl[idx];
        }
        __syncthreads();
        for (int i = tid; i < FB * (HID / 4); i += 320) {
            int r = i >> 7, k4 = i & 127;
            *(float4*)&xs[r][k4 * 4] = *(const float4*)(X + (size_t)stok[r] * HID + k4 * 4);
        }
        __syncthreads();

        {
            const int c = tid;
            if (c < CC) {
                const float* wr = W + (size_t)(g * CC + c) * HID;
                float acc[FB];
#pragma unroll
                for (int r = 0; r < FB; ++r) acc[r] = 0.f;
                for (int k4 = 0; k4 < HID / 4; ++k4) {
                    float4 w4 = *(const float4*)(wr + k4 * 4);
#pragma unroll
                    for (int r = 0; r < FB; ++r) {
                        float4 xv = *(const float4*)&xs[r][k4 * 4];
                        acc[r] = fmaf(xv.x, w4.x, acc[r]);
                        acc[r] = fmaf(xv.y, w4.y, acc[r]);
                        acc[r] = fmaf(xv.z, w4.z, acc[r]);
                        acc[r] = fmaf(xv.w, w4.w, acc[r]);
                    }
                }
                float bias = bq[g * CC + c];
#pragma unroll
                for (int r = 0; r < FB; ++r)
                    vals[r][c] = acc[r] + bias + gum[((size_t)stok[r] * GG + g) * CC + c];
            }
        }
        __syncthreads();

        const int lane = tid & 63;
        const int wvv  = tid >> 6;
        if (wvv < FB) {
            const int r = wvv;
            if (r < nr) {
                float b = -3.0e38f; int bi = 0;
#pragma unroll
                for (int j = 0; j < 5; ++j) {
                    int c = lane + j * 64;
                    float v = vals[r][c];
                    if (v > b || (v == b && c < bi)) { b = v; bi = c; }
                }
#pragma unroll
                for (int m = 32; m; m >>= 1) {
                    float ob = __shfl_xor(b, m, 64);
                    int  obi = __shfl_xor(bi, m, 64);
                    if (ob > b || (ob == b && obi < bi)) { b = ob; bi = obi; }
                }
                int tok = stok[r];
                float2 cvv = *(const float2*)(cv + ((size_t)(g * CC + bi)) * DHALF + lane * 2);
                *(float2*)(out + (size_t)tok * 256 + g * DHALF + lane * 2) = cvv;
            }
        }
        __syncthreads();
    }
}

__global__ __launch_bounds__(256) void perpk(
    const float* __restrict__ meanAcc, float* __restrict__ outp, int ntot)
{
    __shared__ float red0[256];
    __shared__ float red1[256];
    const float invn = 1.f / (float)ntot;
    float h0 = 0.f, h1 = 0.f;
    for (int c = threadIdx.x; c < CC; c += 256) {
        float p0 = meanAcc[c]      * invn;
        float p1 = meanAcc[CC + c] * invn;
        h0 -= p0 * logf(p0 + 1e-7f);
        h1 -= p1 * logf(p1 + 1e-7f);
    }
    red0[threadIdx.x] = h0; red1[threadIdx.x] = h1;
    __syncthreads();
    for (int s = 128; s; s >>= 1) {
        if (threadIdx.x < (unsigned)s) {
            red0[threadIdx.x] += red0[threadIdx.x + s];
            red1[threadIdx.x] += red1[threadIdx.x + s];
        }
        __syncthreads();
    }
    if (threadIdx.x == 0) outp[0] = expf(red0[0]) + expf(red1[0]);
}

extern "C" void kernel_launch(void* const* d_in, const int* in_sizes, int n_in,
                              void* d_out, int out_size, void* d_ws, size_t ws_size,
                              hipStream_t stream) {
    const float* x      = (const float*)d_in[0];
    const float* gumbel = (const float*)d_in[1];
    const float* Wq     = (const float*)d_in[2];
    const float* bq     = (const float*)d_in[3];
    const float* cv     = (const float*)d_in[4];
    float* out = (float*)d_out;

    const int NT = in_sizes[0] / HID;       // 32768 tokens

    char* wsc = (char*)d_ws;
    float* meanAcc = (float*)wsc;                          // 640 f
    int*   cnt     = (int*)(wsc + 2560);                   // 2 ints
    int*   flags0  = (int*)(wsc + 4096);                   // 32768 ints
    int*   flags1  = (int*)(wsc + 135168);                 // 32768 ints
    unsigned short* Wh = (unsigned short*)(wsc + 266240);  // 640*512 f16 row-major

    zero_misc<<<1, 256, 0, stream>>>(meanAcc, cnt);
    convert_f16<<<(GC * HID / 8 + 255) / 256, 256, 0, stream>>>(Wq, Wh, GC * HID / 8);

    const int nwg = (NT / 64) * 2;          // 1024 blocks
    fused<<<nwg, 512, 0, stream>>>(x, Wh, bq, gumbel, cv, out,
                                   meanAcc, cnt, flags0, flags1);

    fixup<<<256, 320, 0, stream>>>(x, Wq, bq, gumbel, cv, out, flags0, flags1, cnt);
    perpk<<<1, 256, 0, stream>>>(meanAcc, out + (size_t)out_size - 1, NT);
}